// Round 1
// baseline (294.046 us; speedup 1.0000x reference)
//
#include <hip/hip_runtime.h>

#define PI_F 3.14159265358979323846f

// ws layout (bytes):
//   24576    : maxz — u32 maxraw[3*32] then maxdiff[3] (zeroed by bin block 0)
//   32768    : packed hist u8: 3 planes × 32 hists × 262144 bins = 24 MB
//   25198592 : bucket regions: 4096 bin-blocks × 24640 B each
//              (64 B header: u16 off[25]; 24576 B data: 12288 u16 in-band ids
//               segmented by bucket = plane*8 + band)  -> ws end ≈ 126.2 MB
#define MAXZ_OFF_B   24576
#define HIST_OFF_B   32768
#define BUCK_OFF_B   25198592
#define REGION_U16   12320          // region stride in u16 units (24640 B)

// Correctly-rounded a/20000 via Markstein refinement (bit-exact RN).
__device__ inline float div20000(float a) {
    const float r = 1.0f / 20000.0f;
    float q0 = a * r;
    float e = fmaf(-20000.0f, q0, a);
    return fmaf(e, r, q0);
}

__device__ inline int bin1(float v) {
    float f = rintf(div20000(v + 10000.0f) * 512.0f);
    return (int)fminf(fmaxf(f, 0.0f), 511.0f);
}

// Pass 1: 4096 blocks = (xcd[0:2], i4[3:9], hh[10:11]), 4 rows/block,
// XCD-pinned (wg&7 == h&7). Trig computed with the EXACT same expressions as
// previous builds -> bit-identical bins. NEW: instead of writing raw
// (iC,iB,iA) triples for scan to band-test ~13x per point, each block
// bucket-sorts its 4096 points × 3 planes into 24 (plane,band) segments:
// LDS atomicAdd rank -> thread-0 prefix -> compacted u16 in-band ids written
// to a fixed 24 KB region. Ranks are nondeterministic but counts are exact,
// so downstream histograms are bit-identical.
// Block 0 zeroes maxz + out (ordered before scan/loss by kernel boundary).
__global__ __launch_bounds__(256) void bin_kernel(
    const float* __restrict__ pred, const float* __restrict__ gt,
    unsigned short* __restrict__ buck, unsigned* __restrict__ maxz,
    float* __restrict__ out) {
    __shared__ float sct[4], sst[4];
    __shared__ unsigned cnt[24];
    __shared__ unsigned off[25];
    const int tid = threadIdx.x, wg = blockIdx.x;
    const int xcd = wg & 7, i4 = (wg >> 3) & 127, hh = wg >> 10;
    const int h = (hh << 3) | xcd;
    if (wg == 0) {
        if (tid < 128) maxz[tid] = 0u;
        if (tid == 128) out[0] = 0.0f;
    }
    if (tid < 24) cnt[tid] = 0u;
    if (tid < 4) {
        float fi = (float)(i4 * 4 + tid);
        float theta = -PI_F * (fi / 511.0f - 0.5f);
        sct[tid] = cosf(theta);
        sst[tid] = sinf(theta);
    }
    float cp[4], sp[4];
    #pragma unroll
    for (int k = 0; k < 4; ++k) {
        float fj = (float)(tid * 4 + k);
        float phi = PI_F * ((2.0f * fj) / 1023.0f - 1.0f);
        cp[k] = cosf(phi);
        sp[k] = sinf(phi);
    }
    __syncthreads();
    const float* img = ((h >> 4) ? gt : pred) + ((h & 15) << 19);
    // item = [bucket:5][rank:12][id:15] — rank <= 4095 (<=4096 items/bucket)
    unsigned items[48];
    #pragma unroll
    for (int r = 0; r < 4; ++r) {
        const int i = i4 * 4 + r;
        const float4 d4 = *(const float4*)(img + (i << 10) + (tid << 2));
        const float ct = sct[r], st = sst[r];
        #pragma unroll
        for (int k = 0; k < 4; ++k) {
            float d = (&d4.x)[k];
            float aA = cp[k] * ct;              // identical op order to r3/r5
            float aB = sp[k] * ct;
            float A = (d * aA) * 1000.0f;
            float B = (d * aB) * 1000.0f;
            float C = (d * (-st)) * 1000.0f;
            int iA = bin1(A), iB = bin1(B), iC = bin1(C);
            // plane0: y=iB,x=iA; plane1: y=iC,x=iA; plane2: y=iC,x=iB
            unsigned b0 = (unsigned)(iB >> 6);
            unsigned b1 = 8u + (unsigned)(iC >> 6);
            unsigned b2 = 16u + (unsigned)(iC >> 6);
            unsigned id0 = ((unsigned)(iB & 63) << 9) | (unsigned)iA;
            unsigned id1 = ((unsigned)(iC & 63) << 9) | (unsigned)iA;
            unsigned id2 = ((unsigned)(iC & 63) << 9) | (unsigned)iB;
            unsigned r0 = atomicAdd(&cnt[b0], 1u);
            unsigned r1 = atomicAdd(&cnt[b1], 1u);
            unsigned r2 = atomicAdd(&cnt[b2], 1u);
            const int base = (r * 4 + k) * 3;
            items[base + 0] = (b0 << 27) | (r0 << 15) | id0;
            items[base + 1] = (b1 << 27) | (r1 << 15) | id1;
            items[base + 2] = (b2 << 27) | (r2 << 15) | id2;
        }
    }
    __syncthreads();
    if (tid == 0) {
        unsigned s = 0;
        #pragma unroll
        for (int b = 0; b < 24; ++b) { off[b] = s; s += cnt[b]; }
        off[24] = s;                            // == 12288
    }
    __syncthreads();
    unsigned short* reg = buck + (size_t)wg * REGION_U16;
    if (tid < 25) reg[tid] = (unsigned short)off[tid];
    unsigned short* data = reg + 32;            // data after 64 B header
    // scatter: same-bucket lanes get consecutive ranks -> stores coalesce,
    // and each 24 KB region is fully written (sum of counts == 12288).
    #pragma unroll
    for (int t = 0; t < 48; ++t) {
        const unsigned it = items[t];
        data[off[it >> 27] + ((it >> 15) & 4095u)] =
            (unsigned short)(it & 32767u);
    }
}

// Pass 2: WG = (plane, h, band); 1024 threads, 2 blocks/CU = 32 waves/CU.
// Each wave streams the block's (plane,band) segments of 8 of the 128
// bin-block regions for this h: contiguous u16 ids, exactly one visit per
// point per plane — no band tests, no wasted rows. LDS hist + pack unchanged.
// blockIdx bits: [0:2]=xcd==h&7 (L2 pin), [3:4]=h>>3, [5:9]=X (LPT order).
__global__ __launch_bounds__(1024, 8) void scan_kernel(
    const unsigned short* __restrict__ buck, unsigned* __restrict__ hp,
    unsigned* __restrict__ maxraw) {
    __shared__ unsigned lh[16384];              // 64 rows × 512 bins, u16×2
    __shared__ unsigned s4[16];
    const int tid = threadIdx.x, wg = blockIdx.x;
    const int xcd = wg & 7, hhi = (wg >> 3) & 3;
    const int X = wg >> 5;                      // 0..23
    const int pair = X / 6, idx6 = X % 6;
    const int plane = idx6 >> 1;
    const int band = (idx6 & 1) ? (4 + pair) : (3 - pair);
    const int h = (hhi << 3) | xcd;
    const int bucket = plane * 8 + band;

    #pragma unroll
    for (int k = 0; k < 4; ++k)
        *(uint4*)&lh[(k << 12) + (tid << 2)] = make_uint4(0, 0, 0, 0);
    __syncthreads();

    const int wid = tid >> 6, lane = tid & 63;
    for (int i4 = wid; i4 < 128; i4 += 16) {
        const unsigned short* reg =
            buck + (size_t)(xcd | (i4 << 3) | (hhi << 10)) * REGION_U16;
        const int lo = reg[bucket], hi = reg[bucket + 1];
        const unsigned short* data = reg + 32 + lo;
        for (int j = lane; j < hi - lo; j += 64) {
            const unsigned id = data[j];
            atomicAdd(&lh[id >> 1], 1u << ((id & 1u) << 4));
        }
    }
    __syncthreads();

    // pack to u8 (sat 255; downstream clamps at 100) + raw band max
    unsigned m = 0;
    unsigned* gout = hp + ((plane * 32 + h) << 16) + (band << 13);
    #pragma unroll
    for (int k = 0; k < 8; ++k) {
        int w = (k << 10) + tid;
        unsigned v0 = lh[2 * w], v1 = lh[2 * w + 1];
        unsigned c0 = v0 & 65535u, c1 = v0 >> 16;
        unsigned c2 = v1 & 65535u, c3 = v1 >> 16;
        m = max(max(m, max(c0, c1)), max(c2, c3));
        gout[w] = min(c0, 255u) | (min(c1, 255u) << 8) |
                  (min(c2, 255u) << 16) | (min(c3, 255u) << 24);
    }
    #pragma unroll
    for (int o = 32; o; o >>= 1) m = max(m, (unsigned)__shfl_down((int)m, o));
    if ((tid & 63) == 0) s4[tid >> 6] = m;
    __syncthreads();
    if (tid == 0) {
        #pragma unroll
        for (int k = 1; k < 16; ++k) m = max(m, s4[k]);
        atomicMax(&maxraw[plane * 32 + h], m);
    }
}

__device__ inline float blockMaxF(float v) {
    #pragma unroll
    for (int o = 32; o; o >>= 1) v = fmaxf(v, __shfl_down(v, o));
    __shared__ float s[4];
    if ((threadIdx.x & 63) == 0) s[threadIdx.x >> 6] = v;
    __syncthreads();
    if (threadIdx.x == 0) v = fmaxf(fmaxf(s[0], s[1]), fmaxf(s[2], s[3]));
    return v;
}

__device__ inline float blockSumF(float v) {
    #pragma unroll
    for (int o = 32; o; o >>= 1) v += __shfl_down(v, o);
    __shared__ float s[4];
    if ((threadIdx.x & 63) == 0) s[threadIdx.x >> 6] = v;
    __syncthreads();
    if (threadIdx.x == 0) v = (s[0] + s[1]) + (s[2] + s[3]);
    return v;
}

// 768 blocks = 3 planes × 16 b × 16 chunks; uint4 loads, 16 bins/word-quad.
__global__ void maxdiff_kernel(const unsigned* __restrict__ hp,
                               const unsigned* __restrict__ maxraw,
                               unsigned* __restrict__ maxdiff) {
    int blk = blockIdx.x;
    int b = blk & 15, chunk = (blk >> 4) & 15, plane = blk >> 8;
    const unsigned* P = hp + ((plane * 32 + b) << 16) + (chunk << 12);
    const unsigned* G = P + (16 << 16);
    float nP = fminf((float)maxraw[plane * 32 + b], 100.0f);
    float nG = fminf((float)maxraw[plane * 32 + 16 + b], 100.0f);
    float m = 0.0f;
    #pragma unroll
    for (int k = 0; k < 4; ++k) {
        uint4 wp = *(const uint4*)&P[(k << 10) + (threadIdx.x << 2)];
        uint4 wg = *(const uint4*)&G[(k << 10) + (threadIdx.x << 2)];
        #pragma unroll
        for (int w = 0; w < 4; ++w) {
            unsigned up = (&wp.x)[w], ug = (&wg.x)[w];
            #pragma unroll
            for (int s = 0; s < 32; s += 8) {
                float pn = fminf((float)((up >> s) & 255u), 100.0f) / nP;
                float gn = fminf((float)((ug >> s) & 255u), 100.0f) / nG;
                m = fmaxf(m, fabsf(pn - gn));
            }
        }
    }
    m = blockMaxF(m);
    if (threadIdx.x == 0) atomicMax(&maxdiff[plane], __float_as_uint(m));
}

// Accumulates directly into out[0] (pre-zeroed by bin block 0):
// blocksum/2^22 is an exact power-of-2 scale, then one atomicAdd per block.
__global__ void loss_kernel(const unsigned* __restrict__ hp,
                            const unsigned* __restrict__ maxraw,
                            const unsigned* __restrict__ maxdiff,
                            float* __restrict__ out) {
    int blk = blockIdx.x;
    int b = blk & 15, chunk = (blk >> 4) & 15, plane = blk >> 8;
    const unsigned* P = hp + ((plane * 32 + b) << 16) + (chunk << 12);
    const unsigned* G = P + (16 << 16);
    float c = 0.2f * __uint_as_float(maxdiff[plane]);
    float nP = fminf((float)maxraw[plane * 32 + b], 100.0f);
    float nG = fminf((float)maxraw[plane * 32 + 16 + b], 100.0f);
    float acc = 0.0f;
    #pragma unroll
    for (int k = 0; k < 4; ++k) {
        uint4 wp = *(const uint4*)&P[(k << 10) + (threadIdx.x << 2)];
        uint4 wg = *(const uint4*)&G[(k << 10) + (threadIdx.x << 2)];
        #pragma unroll
        for (int w = 0; w < 4; ++w) {
            unsigned up = (&wp.x)[w], ug = (&wg.x)[w];
            #pragma unroll
            for (int s = 0; s < 32; s += 8) {
                float pn = fminf((float)((up >> s) & 255u), 100.0f) / nP;
                float gn = fminf((float)((ug >> s) & 255u), 100.0f) / nG;
                float d = fabsf(pn - gn);
                acc += (d <= c) ? d : (d * d + c * c) / (2.0f * c);
            }
        }
    }
    acc = blockSumF(acc);
    if (threadIdx.x == 0) atomicAdd(out, acc / 4194304.0f);
}

extern "C" void kernel_launch(void* const* d_in, const int* in_sizes, int n_in,
                              void* d_out, int out_size, void* d_ws, size_t ws_size,
                              hipStream_t stream) {
    const float* pred = (const float*)d_in[0];
    const float* gt   = (const float*)d_in[1];
    float* out        = (float*)d_out;
    char* ws          = (char*)d_ws;

    unsigned* maxz    = (unsigned*)(ws + MAXZ_OFF_B);
    unsigned* maxraw  = maxz;
    unsigned* maxdiff = maxz + 96;
    unsigned* hp      = (unsigned*)(ws + HIST_OFF_B);
    unsigned short* buck = (unsigned short*)(ws + BUCK_OFF_B);

    bin_kernel<<<4096, 256, 0, stream>>>(pred, gt, buck, maxz, out);
    scan_kernel<<<768, 1024, 0, stream>>>(buck, hp, maxraw);
    maxdiff_kernel<<<768, 256, 0, stream>>>(hp, maxraw, maxdiff);
    loss_kernel<<<768, 256, 0, stream>>>(hp, maxraw, maxdiff, out);
}

// Round 2
// 210.981 us; speedup vs baseline: 1.3937x; 1.3937x over previous
//
#include <hip/hip_runtime.h>

#define PI_F 3.14159265358979323846f

// ws layout (bytes):
//   24576    : maxz — u32 maxraw[3*32] then maxdiff[3] (zeroed by bin block 0)
//   32768    : packed hist u8: 3 planes × 32 hists × 262144 bins = 24 MB
//   25198592 : bucket regions: 4096 bin-blocks × 24640 B each
//              (64 B header: u16 off[25]; 24576 B data: 12288 u16 in-band ids
//               segmented by bucket = plane*8 + band)  -> ws end ≈ 126.2 MB
#define MAXZ_OFF_B   24576
#define HIST_OFF_B   32768
#define BUCK_OFF_B   25198592
#define REGION_U16   12320          // region stride in u16 units (24640 B)

// Correctly-rounded a/20000 via Markstein refinement (bit-exact RN).
__device__ inline float div20000(float a) {
    const float r = 1.0f / 20000.0f;
    float q0 = a * r;
    float e = fmaf(-20000.0f, q0, a);
    return fmaf(e, r, q0);
}

__device__ inline int bin1(float v) {
    float f = rintf(div20000(v + 10000.0f) * 512.0f);
    return (int)fminf(fmaxf(f, 0.0f), 511.0f);
}

// Pass 1: 4096 blocks = (xcd[0:2], i4[3:9], hh[10:11]), 4 rows/block,
// XCD-pinned (wg&7 == h&7). Trig computed with the EXACT same expressions as
// previous builds -> bit-identical bins. Bucket-sort of 4096 points × 3
// planes into 24 (plane,band) segments, with two fixes vs the previous
// version (which was LDS-atomic-serialization + scattered-global-store
// bound, 131.7 µs @ 27% VALUBusy):
//  * rank counters replicated 8× (cnt[bucket*8 + tid&7]) — kills the
//    same-address atomic serialization (28.3M conflict cycles); rank <= 511
//    so [bucket:5][rep:3][rank:9][id:15] still packs in 32 bits.
//  * ids scattered into an LDS staging buffer (u16 LDS scatter ~2-way = free)
//    then copied out as exactly 6 coalesced uint4 stores per thread.
// Ranks are nondeterministic but per-bucket counts are exact, so downstream
// histograms are bit-identical.
// Block 0 zeroes maxz + out (ordered before scan/loss by kernel boundary).
__global__ __launch_bounds__(256) void bin_kernel(
    const float* __restrict__ pred, const float* __restrict__ gt,
    unsigned short* __restrict__ buck, unsigned* __restrict__ maxz,
    float* __restrict__ out) {
    __shared__ float sct[4], sst[4];
    __shared__ unsigned cnt[192];               // 24 buckets × 8 replicas
    __shared__ unsigned bsum[24];
    __shared__ unsigned off[25];
    __shared__ __align__(16) unsigned short sdata[12288];
    const int tid = threadIdx.x, wg = blockIdx.x;
    const unsigned rep = (unsigned)(tid & 7);
    const int xcd = wg & 7, i4 = (wg >> 3) & 127, hh = wg >> 10;
    const int h = (hh << 3) | xcd;
    if (wg == 0) {
        if (tid < 128) maxz[tid] = 0u;
        if (tid == 128) out[0] = 0.0f;
    }
    if (tid < 192) cnt[tid] = 0u;
    if (tid < 4) {
        float fi = (float)(i4 * 4 + tid);
        float theta = -PI_F * (fi / 511.0f - 0.5f);
        sct[tid] = cosf(theta);
        sst[tid] = sinf(theta);
    }
    float cp[4], sp[4];
    #pragma unroll
    for (int k = 0; k < 4; ++k) {
        float fj = (float)(tid * 4 + k);
        float phi = PI_F * ((2.0f * fj) / 1023.0f - 1.0f);
        cp[k] = cosf(phi);
        sp[k] = sinf(phi);
    }
    __syncthreads();
    const float* img = ((h >> 4) ? gt : pred) + ((h & 15) << 19);
    // item = [bucket:5][rep:3][rank:9][id:15]
    unsigned items[48];
    #pragma unroll
    for (int r = 0; r < 4; ++r) {
        const int i = i4 * 4 + r;
        const float4 d4 = *(const float4*)(img + (i << 10) + (tid << 2));
        const float ct = sct[r], st = sst[r];
        #pragma unroll
        for (int k = 0; k < 4; ++k) {
            float d = (&d4.x)[k];
            float aA = cp[k] * ct;              // identical op order to r3/r5
            float aB = sp[k] * ct;
            float A = (d * aA) * 1000.0f;
            float B = (d * aB) * 1000.0f;
            float C = (d * (-st)) * 1000.0f;
            int iA = bin1(A), iB = bin1(B), iC = bin1(C);
            // plane0: y=iB,x=iA; plane1: y=iC,x=iA; plane2: y=iC,x=iB
            unsigned b0 = (unsigned)(iB >> 6);
            unsigned b1 = 8u + (unsigned)(iC >> 6);
            unsigned b2 = 16u + (unsigned)(iC >> 6);
            unsigned id0 = ((unsigned)(iB & 63) << 9) | (unsigned)iA;
            unsigned id1 = ((unsigned)(iC & 63) << 9) | (unsigned)iA;
            unsigned id2 = ((unsigned)(iC & 63) << 9) | (unsigned)iB;
            unsigned r0 = atomicAdd(&cnt[(b0 << 3) | rep], 1u);
            unsigned r1 = atomicAdd(&cnt[(b1 << 3) | rep], 1u);
            unsigned r2 = atomicAdd(&cnt[(b2 << 3) | rep], 1u);
            const int base = (r * 4 + k) * 3;
            items[base + 0] = (b0 << 27) | (rep << 24) | (r0 << 15) | id0;
            items[base + 1] = (b1 << 27) | (rep << 24) | (r1 << 15) | id1;
            items[base + 2] = (b2 << 27) | (rep << 24) | (r2 << 15) | id2;
        }
    }
    __syncthreads();
    // 3-level prefix: intra-bucket over 8 replicas, then across 24 buckets,
    // then convert cnt[] to absolute segment bases.
    if (tid < 24) {
        unsigned s = 0;
        #pragma unroll
        for (int r = 0; r < 8; ++r) {
            unsigned t = cnt[(tid << 3) | r];
            cnt[(tid << 3) | r] = s;
            s += t;
        }
        bsum[tid] = s;
    }
    __syncthreads();
    if (tid == 0) {
        unsigned s = 0;
        #pragma unroll
        for (int b = 0; b < 24; ++b) { off[b] = s; s += bsum[b]; }
        off[24] = s;                            // == 12288
    }
    __syncthreads();
    if (tid < 24) {
        unsigned o = off[tid];
        #pragma unroll
        for (int r = 0; r < 8; ++r) cnt[(tid << 3) | r] += o;
    }
    __syncthreads();
    // scatter into LDS staging (u16 scatter in LDS, ~2-way conflicts = free)
    #pragma unroll
    for (int t = 0; t < 48; ++t) {
        const unsigned it = items[t];
        const unsigned slot = (it >> 27) * 8u + ((it >> 24) & 7u);
        sdata[cnt[slot] + ((it >> 15) & 511u)] = (unsigned short)(it & 32767u);
    }
    __syncthreads();
    unsigned short* regG = buck + (size_t)wg * REGION_U16;
    if (tid < 25) regG[tid] = (unsigned short)off[tid];
    // coalesced copy-out: 12288 u16 = 1536 uint4 = 6 per thread exactly
    const uint4* s4p = (const uint4*)sdata;
    uint4* g4 = (uint4*)(regG + 32);            // data after 64 B header
    #pragma unroll
    for (int c = 0; c < 6; ++c) g4[(c << 8) + tid] = s4p[(c << 8) + tid];
}

// Pass 2: WG = (plane, h, band); 1024 threads, 2 blocks/CU = 32 waves/CU.
// Each wave streams the (plane,band) segments of 8 of the 128 bin-block
// regions for this h: contiguous u16 ids read as uint4 (8 ids/lane) with
// <=7-element scalar head/tail for 16B alignment — exactly one visit per
// point per plane, no band tests. LDS hist + pack unchanged.
// blockIdx bits: [0:2]=xcd==h&7 (L2 pin), [3:4]=h>>3, [5:9]=X (LPT order).
__global__ __launch_bounds__(1024, 8) void scan_kernel(
    const unsigned short* __restrict__ buck, unsigned* __restrict__ hp,
    unsigned* __restrict__ maxraw) {
    __shared__ unsigned lh[16384];              // 64 rows × 512 bins, u16×2
    __shared__ unsigned s4[16];
    const int tid = threadIdx.x, wg = blockIdx.x;
    const int xcd = wg & 7, hhi = (wg >> 3) & 3;
    const int X = wg >> 5;                      // 0..23
    const int pair = X / 6, idx6 = X % 6;
    const int plane = idx6 >> 1;
    const int band = (idx6 & 1) ? (4 + pair) : (3 - pair);
    const int h = (hhi << 3) | xcd;
    const int bucket = plane * 8 + band;

    #pragma unroll
    for (int k = 0; k < 4; ++k)
        *(uint4*)&lh[(k << 12) + (tid << 2)] = make_uint4(0, 0, 0, 0);
    __syncthreads();

    const int wid = tid >> 6, lane = tid & 63;
    for (int i4 = wid; i4 < 128; i4 += 16) {
        const unsigned short* reg =
            buck + (size_t)(xcd | (i4 << 3) | (hhi << 10)) * REGION_U16;
        const int lo = reg[bucket], hi = reg[bucket + 1];
        const unsigned short* data = reg + 32;
        int a = (lo + 7) & ~7;                  // first 16B-aligned index
        if (a > hi) a = hi;
        const int head = a - lo;                // <= 7
        if (lane < head) {
            const unsigned id = data[lo + lane];
            atomicAdd(&lh[id >> 1], 1u << ((id & 1u) << 4));
        }
        const int nv = (hi - a) >> 3;           // full uint4 groups
        for (int v = lane; v < nv; v += 64) {
            const uint4 w = *(const uint4*)&data[a + (v << 3)];
            #pragma unroll
            for (int q = 0; q < 4; ++q) {
                const unsigned u = (&w.x)[q];
                const unsigned idl = u & 65535u, idh = u >> 16;
                atomicAdd(&lh[idl >> 1], 1u << ((idl & 1u) << 4));
                atomicAdd(&lh[idh >> 1], 1u << ((idh & 1u) << 4));
            }
        }
        const int tail = (hi - a) & 7;          // <= 7
        if (lane < tail) {
            const unsigned id = data[a + (nv << 3) + lane];
            atomicAdd(&lh[id >> 1], 1u << ((id & 1u) << 4));
        }
    }
    __syncthreads();

    // pack to u8 (sat 255; downstream clamps at 100) + raw band max
    unsigned m = 0;
    unsigned* gout = hp + ((plane * 32 + h) << 16) + (band << 13);
    #pragma unroll
    for (int k = 0; k < 8; ++k) {
        int w = (k << 10) + tid;
        unsigned v0 = lh[2 * w], v1 = lh[2 * w + 1];
        unsigned c0 = v0 & 65535u, c1 = v0 >> 16;
        unsigned c2 = v1 & 65535u, c3 = v1 >> 16;
        m = max(max(m, max(c0, c1)), max(c2, c3));
        gout[w] = min(c0, 255u) | (min(c1, 255u) << 8) |
                  (min(c2, 255u) << 16) | (min(c3, 255u) << 24);
    }
    #pragma unroll
    for (int o = 32; o; o >>= 1) m = max(m, (unsigned)__shfl_down((int)m, o));
    if ((tid & 63) == 0) s4[tid >> 6] = m;
    __syncthreads();
    if (tid == 0) {
        #pragma unroll
        for (int k = 1; k < 16; ++k) m = max(m, s4[k]);
        atomicMax(&maxraw[plane * 32 + h], m);
    }
}

__device__ inline float blockMaxF(float v) {
    #pragma unroll
    for (int o = 32; o; o >>= 1) v = fmaxf(v, __shfl_down(v, o));
    __shared__ float s[4];
    if ((threadIdx.x & 63) == 0) s[threadIdx.x >> 6] = v;
    __syncthreads();
    if (threadIdx.x == 0) v = fmaxf(fmaxf(s[0], s[1]), fmaxf(s[2], s[3]));
    return v;
}

__device__ inline float blockSumF(float v) {
    #pragma unroll
    for (int o = 32; o; o >>= 1) v += __shfl_down(v, o);
    __shared__ float s[4];
    if ((threadIdx.x & 63) == 0) s[threadIdx.x >> 6] = v;
    __syncthreads();
    if (threadIdx.x == 0) v = (s[0] + s[1]) + (s[2] + s[3]);
    return v;
}

// 768 blocks = 3 planes × 16 b × 16 chunks; uint4 loads, 16 bins/word-quad.
__global__ void maxdiff_kernel(const unsigned* __restrict__ hp,
                               const unsigned* __restrict__ maxraw,
                               unsigned* __restrict__ maxdiff) {
    int blk = blockIdx.x;
    int b = blk & 15, chunk = (blk >> 4) & 15, plane = blk >> 8;
    const unsigned* P = hp + ((plane * 32 + b) << 16) + (chunk << 12);
    const unsigned* G = P + (16 << 16);
    float nP = fminf((float)maxraw[plane * 32 + b], 100.0f);
    float nG = fminf((float)maxraw[plane * 32 + 16 + b], 100.0f);
    float m = 0.0f;
    #pragma unroll
    for (int k = 0; k < 4; ++k) {
        uint4 wp = *(const uint4*)&P[(k << 10) + (threadIdx.x << 2)];
        uint4 wg = *(const uint4*)&G[(k << 10) + (threadIdx.x << 2)];
        #pragma unroll
        for (int w = 0; w < 4; ++w) {
            unsigned up = (&wp.x)[w], ug = (&wg.x)[w];
            #pragma unroll
            for (int s = 0; s < 32; s += 8) {
                float pn = fminf((float)((up >> s) & 255u), 100.0f) / nP;
                float gn = fminf((float)((ug >> s) & 255u), 100.0f) / nG;
                m = fmaxf(m, fabsf(pn - gn));
            }
        }
    }
    m = blockMaxF(m);
    if (threadIdx.x == 0) atomicMax(&maxdiff[plane], __float_as_uint(m));
}

// Accumulates directly into out[0] (pre-zeroed by bin block 0):
// blocksum/2^22 is an exact power-of-2 scale, then one atomicAdd per block.
__global__ void loss_kernel(const unsigned* __restrict__ hp,
                            const unsigned* __restrict__ maxraw,
                            const unsigned* __restrict__ maxdiff,
                            float* __restrict__ out) {
    int blk = blockIdx.x;
    int b = blk & 15, chunk = (blk >> 4) & 15, plane = blk >> 8;
    const unsigned* P = hp + ((plane * 32 + b) << 16) + (chunk << 12);
    const unsigned* G = P + (16 << 16);
    float c = 0.2f * __uint_as_float(maxdiff[plane]);
    float nP = fminf((float)maxraw[plane * 32 + b], 100.0f);
    float nG = fminf((float)maxraw[plane * 32 + 16 + b], 100.0f);
    float acc = 0.0f;
    #pragma unroll
    for (int k = 0; k < 4; ++k) {
        uint4 wp = *(const uint4*)&P[(k << 10) + (threadIdx.x << 2)];
        uint4 wg = *(const uint4*)&G[(k << 10) + (threadIdx.x << 2)];
        #pragma unroll
        for (int w = 0; w < 4; ++w) {
            unsigned up = (&wp.x)[w], ug = (&wg.x)[w];
            #pragma unroll
            for (int s = 0; s < 32; s += 8) {
                float pn = fminf((float)((up >> s) & 255u), 100.0f) / nP;
                float gn = fminf((float)((ug >> s) & 255u), 100.0f) / nG;
                float d = fabsf(pn - gn);
                acc += (d <= c) ? d : (d * d + c * c) / (2.0f * c);
            }
        }
    }
    acc = blockSumF(acc);
    if (threadIdx.x == 0) atomicAdd(out, acc / 4194304.0f);
}

extern "C" void kernel_launch(void* const* d_in, const int* in_sizes, int n_in,
                              void* d_out, int out_size, void* d_ws, size_t ws_size,
                              hipStream_t stream) {
    const float* pred = (const float*)d_in[0];
    const float* gt   = (const float*)d_in[1];
    float* out        = (float*)d_out;
    char* ws          = (char*)d_ws;

    unsigned* maxz    = (unsigned*)(ws + MAXZ_OFF_B);
    unsigned* maxraw  = maxz;
    unsigned* maxdiff = maxz + 96;
    unsigned* hp      = (unsigned*)(ws + HIST_OFF_B);
    unsigned short* buck = (unsigned short*)(ws + BUCK_OFF_B);

    bin_kernel<<<4096, 256, 0, stream>>>(pred, gt, buck, maxz, out);
    scan_kernel<<<768, 1024, 0, stream>>>(buck, hp, maxraw);
    maxdiff_kernel<<<768, 256, 0, stream>>>(hp, maxraw, maxdiff);
    loss_kernel<<<768, 256, 0, stream>>>(hp, maxraw, maxdiff, out);
}